// Round 12
// baseline (88.038 us; speedup 1.0000x reference)
//
#include <hip/hip_runtime.h>
#include <hip/hip_bf16.h>
#include <cstddef>
#include <cstdint>

#define BB 4
#define CC 256
#define II 32
#define NN 4096

// 1/sqrt(32) * log2(e): fold softmax scale AND exp->exp2 conversion into q.
#define SCALE_Q 0.25505572751402893f

typedef __attribute__((ext_vector_type(8))) short bf16x8;
typedef __attribute__((ext_vector_type(16))) float f32x16;

static __device__ __forceinline__ int cvt_pk_bf16(float lo, float hi) {
  int d;
  asm("v_cvt_pk_bf16_f32 %0, %1, %2" : "=v"(d) : "v"(lo), "v"(hi));
  return d;
}
static __device__ __forceinline__ void perm32swap_f(float& a, float& b) {
  asm("v_permlane32_swap_b32 %0, %1" : "+v"(a), "+v"(b));
}
static __device__ __forceinline__ float max3f(float a, float b, float c) {
  float d;
  asm("v_max3_f32 %0, %1, %2, %3" : "=v"(d) : "v"(a), "v"(b), "v"(c));
  return d;
}
static __device__ __forceinline__ f32x16 zero16() {
  f32x16 z;
#pragma unroll
  for (int i = 0; i < 16; ++i) z[i] = 0.0f;
  return z;
}
// VGPR-form S-MFMA (keeps the softmax operand out of AGPRs).
// s_nop 1 guards VALU-write(C init)->MFMA-read; trailing s_nop 7x2 guards
// MFMA-write->VALU-read of the result (hazard recognizer also sees the defs).
static __device__ __forceinline__ void mfma_bf16_first(bf16x8 a, bf16x8 b, f32x16& c) {
  asm("s_nop 1\n\tv_mfma_f32_32x32x16_bf16 %0, %1, %2, %0"
      : "+v"(c) : "v"(a), "v"(b));
}
static __device__ __forceinline__ void mfma_bf16_last(bf16x8 a, bf16x8 b, f32x16& c) {
  asm("v_mfma_f32_32x32x16_bf16 %0, %1, %2, %0\n\ts_nop 7\n\ts_nop 7"
      : "+v"(c) : "v"(a), "v"(b));
}
static __device__ __forceinline__ bf16x8 pack8(float f0, float f1, float f2,
    float f3, float f4, float f5, float f6, float f7) {
  union { int w[4]; bf16x8 v8; } u;
  u.w[0] = cvt_pk_bf16(f0, f1);
  u.w[1] = cvt_pk_bf16(f2, f3);
  u.w[2] = cvt_pk_bf16(f4, f5);
  u.w[3] = cvt_pk_bf16(f6, f7);
  return u.v8;
}
static __device__ __forceinline__ ushort f2bfu(float f) {
  union { __hip_bfloat16 h; ushort u; } cv;
  cv.h = __float2bfloat16(f);
  return cv.u;
}
static __device__ __forceinline__ int pack4_fp8(float a, float b, float c, float d) {
  int r = __builtin_amdgcn_cvt_pk_fp8_f32(a, b, 0, false);
  r = __builtin_amdgcn_cvt_pk_fp8_f32(c, d, r, true);
  return r;
}
static __device__ __forceinline__ unsigned char f2fp8(float f) {
  return (unsigned char)(__builtin_amdgcn_cvt_pk_fp8_f32(f, f, 0, false) & 0xff);
}

// Layouts:
//  qT/kT (bf16): [b][mt=n/32][frag=i/16][p]; p = 256*((i>>3)&1) + 8*(n&31) + (i&7)
//  vT8  (fp8):   [b][ct=c/32][nt=n/16][p];  p = 256*((n>>3)&1) + 8*(c&31) + (n&7)
//                (ct-major: a wave's 16 PV loads are base + kt*512, contiguous)

// ---- fused qkv projection: 5 waves/block, og = wave id ---------------------
// grid (B, N/32), block 320. Wave 0: q+k tiles; waves 1..4: v rows (og-1)*64..
// All 5 waves read the SAME x slab -> L1/L2 dedup (x traffic ~1x, was 5x).
// Per-wave code identical to the proven round-7 blocks.
__global__ __launch_bounds__(320, 2) void proj_mfma(
    const float* __restrict__ Wq, const float* __restrict__ bq,
    const float* __restrict__ Wk, const float* __restrict__ bk,
    const float* __restrict__ Wv, const float* __restrict__ bv,
    const float* __restrict__ x,
    ushort* __restrict__ qT, ushort* __restrict__ kT,
    unsigned char* __restrict__ vT8) {
  const int tid = threadIdx.x;
  const int og = tid >> 6;      // 0..4 (wave id)
  const int lane = tid & 63;
  const int l31 = lane & 31;
  const int h = lane >> 5;
  const int b = blockIdx.x;
  const int n0 = blockIdx.y * 32;

  const float* xb = x + (size_t)b * CC * NN + n0 + l31;
  const float* wr0 = (og == 0) ? (Wq + (size_t)l31 * CC)
                               : (Wv + (size_t)((og - 1) * 64 + l31) * CC);
  const float* wr1 = (og == 0) ? (Wk + (size_t)l31 * CC)
                               : (Wv + (size_t)((og - 1) * 64 + 32 + l31) * CC);

  f32x16 acc0 = zero16(), acc1 = zero16();
#pragma unroll 4
  for (int ks = 0; ks < 16; ++ks) {
    const int c = ks * 16 + h * 8;
    const float* xp = xb + (size_t)c * NN;
    bf16x8 xf = pack8(xp[0], xp[(size_t)1 * NN], xp[(size_t)2 * NN],
                      xp[(size_t)3 * NN], xp[(size_t)4 * NN], xp[(size_t)5 * NN],
                      xp[(size_t)6 * NN], xp[(size_t)7 * NN]);
    float4 wa = *(const float4*)(wr0 + c);
    float4 wb = *(const float4*)(wr0 + c + 4);
    bf16x8 wf0 = pack8(wa.x, wa.y, wa.z, wa.w, wb.x, wb.y, wb.z, wb.w);
    float4 wc = *(const float4*)(wr1 + c);
    float4 wd = *(const float4*)(wr1 + c + 4);
    bf16x8 wf1 = pack8(wc.x, wc.y, wc.z, wc.w, wd.x, wd.y, wd.z, wd.w);
    acc0 = __builtin_amdgcn_mfma_f32_32x32x16_bf16(wf0, xf, acc0, 0, 0, 0);
    acc1 = __builtin_amdgcn_mfma_f32_32x32x16_bf16(wf1, xf, acc1, 0, 0, 0);
  }

  if (og == 0) {
    ushort* qb = qT + (size_t)(b * 128 + (n0 >> 5)) * 1024;
    ushort* kb = kT + (size_t)(b * 128 + (n0 >> 5)) * 1024;
#pragma unroll
    for (int r = 0; r < 16; ++r) {
      const int i = (r & 3) + 8 * (r >> 2) + 4 * h;
      const size_t off = (size_t)(i >> 4) * 512 + ((i >> 3) & 1) * 256 + 8 * l31 + (i & 7);
      qb[off] = f2bfu((acc0[r] + bq[i]) * SCALE_Q);
      kb[off] = f2bfu(acc1[r] + bk[i]);
    }
  } else {
    const int n = n0 + l31;
    const size_t nsub = (size_t)(n >> 4) * 512 + ((size_t)((n >> 3) & 1)) * 256 + (n & 7);
    const size_t bbase = (size_t)b * (1 << 20);
#pragma unroll
    for (int r = 0; r < 16; ++r) {
      const int rp = (r & 3) + 8 * (r >> 2) + 4 * h;
      const int c0 = (og - 1) * 64 + rp;
      const int c1 = c0 + 32;
      vT8[bbase + (size_t)(c0 >> 5) * 131072 + nsub + (c0 & 31) * 8] = f2fp8(acc0[r] + bv[c0]);
      vT8[bbase + (size_t)(c1 >> 5) * 131072 + nsub + (c1 & 31) * 8] = f2fp8(acc1[r] + bv[c1]);
    }
  }
}

// ---- flash attention: 8-wave coop, software-pipelined (P double-buffer) ----
// 1-D grid 512, block 512. Per iteration t: S(t) MFMA (VGPR-form asm) then
// PV(t-1) MFMA (builtin, AGPR acc), then softmax(t) -> pbuf[t&1].
__global__ __launch_bounds__(512, 4) void flash_coop(
    const ushort* __restrict__ qT, const ushort* __restrict__ kT,
    const unsigned char* __restrict__ vT8, const float* __restrict__ x,
    const float* __restrict__ gamma, float* __restrict__ out) {
  __shared__ __align__(16) unsigned char pbuf[2][32 * 264];  // P fp8 [q][m_local]
  __shared__ float mlds[264];  // per-wave rowmax  [w*33 + q]
  __shared__ float slds[264];  // per-wave rowsum  [w*33 + q]

  const int tid = threadIdx.x;
  const int lane = tid & 63;
  const int w = tid >> 6;
  const int q = lane & 31;
  const int h = lane >> 5;

  const int wg = blockIdx.x;
  const int xcd = wg & 7;
  const int b = xcd >> 1;
  const int nt = ((xcd & 1) << 6) + (wg >> 3);
  const int n0 = nt * 32;

  const ushort* qb = qT + (size_t)(b * 128 + nt) * 1024 + lane * 8;
  const bf16x8 qf0 = *reinterpret_cast<const bf16x8*>(qb);
  const bf16x8 qf1 = *reinterpret_cast<const bf16x8*>(qb + 512);

  const ushort* ktb = kT + (size_t)b * 128 * 1024;
  const unsigned char* vtb = vT8 + (size_t)b * (1 << 20) + (size_t)w * 131072;

  f32x16 accA = zero16(), accB = zero16();
  float m_run = -1e30f, l_run = 0.0f;

  // ---------------- prologue: tile 0 S + softmax -> pbuf[0] ----------------
  {
    const ushort* kc = ktb + (size_t)(0 * 8 + w) * 1024 + lane * 8;
    const bf16x8 kf0 = *reinterpret_cast<const bf16x8*>(kc);
    const bf16x8 kf1 = *reinterpret_cast<const bf16x8*>(kc + 512);
    f32x16 st = zero16();
    mfma_bf16_first(kf0, qf0, st);
    mfma_bf16_last(kf1, qf1, st);

    float m0 = max3f(st[0], st[1], st[2]);
    float m1 = max3f(st[3], st[4], st[5]);
    float m2 = max3f(st[6], st[7], st[8]);
    float m3 = max3f(st[9], st[10], st[11]);
    m0 = max3f(st[12], st[13], m0);
    m1 = max3f(st[14], st[15], m1);
    float mx = max3f(m0, m1, fmaxf(m2, m3));
    float sw1 = mx, sw2 = mx;
    perm32swap_f(sw1, sw2);
    if (lane < 32) mlds[w * 33 + q] = fmaxf(sw1, sw2);
    __syncthreads();
    float tmax = mlds[q];
#pragma unroll
    for (int i = 1; i < 8; ++i) tmax = fmaxf(tmax, mlds[i * 33 + q]);
    m_run = tmax;

#pragma unroll
    for (int r = 0; r < 16; ++r) st[r] = __builtin_amdgcn_exp2f(st[r] - m_run);
    float s0 = ((st[0] + st[1]) + (st[2] + st[3])) +
               ((st[4] + st[5]) + (st[6] + st[7]));
    float s1 = ((st[8] + st[9]) + (st[10] + st[11])) +
               ((st[12] + st[13]) + (st[14] + st[15]));
    float pssum = s0 + s1;
    float pa = pssum, pb = pssum;
    perm32swap_f(pa, pb);
    if (lane < 32) slds[w * 33 + q] = pa + pb;
#pragma unroll
    for (int rg = 0; rg < 4; ++rg) {
      const int pk = pack4_fp8(st[rg * 4], st[rg * 4 + 1], st[rg * 4 + 2], st[rg * 4 + 3]);
      *reinterpret_cast<int*>(&pbuf[0][q * 264 + w * 32 + rg * 8 + h * 4]) = pk;
    }
    __syncthreads();
    float tsum = slds[q];
#pragma unroll
    for (int i = 1; i < 8; ++i) tsum += slds[i * 33 + q];
    l_run = tsum;
  }

  // ---------------- main loop: t = 1..15 -----------------------------------
  for (int t = 1; t < 16; ++t) {
    const int pv = t - 1;           // PV consumes tile t-1
    const int pcur = pv & 1;
    const int pnext = t & 1;

    // S(t) MFMA (VGPR form)
    const ushort* kc = ktb + (size_t)(t * 8 + w) * 1024 + lane * 8;
    const bf16x8 kf0 = *reinterpret_cast<const bf16x8*>(kc);
    const bf16x8 kf1 = *reinterpret_cast<const bf16x8*>(kc + 512);
    f32x16 st = zero16();
    __builtin_amdgcn_s_setprio(1);
    mfma_bf16_first(kf0, qf0, st);
    mfma_bf16_last(kf1, qf1, st);

    // PV(t-1): two independent chains, contiguous V (base + kt*512)
    const unsigned char* vc = vtb + (size_t)(pv * 16) * 512 + lane * 8;
#pragma unroll
    for (int kp = 0; kp < 8; ++kp) {
      const long vfA = *reinterpret_cast<const long*>(vc + (2 * kp) * 512);
      const long pfA = *reinterpret_cast<const long*>(&pbuf[pcur][q * 264 + (2 * kp) * 16 + h * 8]);
      accA = __builtin_amdgcn_mfma_f32_32x32x16_fp8_fp8(vfA, pfA, accA, 0, 0, 0);
      const long vfB = *reinterpret_cast<const long*>(vc + (2 * kp + 1) * 512);
      const long pfB = *reinterpret_cast<const long*>(&pbuf[pcur][q * 264 + (2 * kp + 1) * 16 + h * 8]);
      accB = __builtin_amdgcn_mfma_f32_32x32x16_fp8_fp8(vfB, pfB, accB, 0, 0, 0);
    }
    __builtin_amdgcn_s_setprio(0);

    // softmax(t)
    float m0 = max3f(st[0], st[1], st[2]);
    float m1 = max3f(st[3], st[4], st[5]);
    float m2 = max3f(st[6], st[7], st[8]);
    float m3 = max3f(st[9], st[10], st[11]);
    m0 = max3f(st[12], st[13], m0);
    m1 = max3f(st[14], st[15], m1);
    float mx = max3f(m0, m1, fmaxf(m2, m3));
    float sw1 = mx, sw2 = mx;
    perm32swap_f(sw1, sw2);
    if (lane < 32) mlds[w * 33 + q] = fmaxf(sw1, sw2);
    __syncthreads();  // B1: mlds(t) ready
    float tmax = mlds[q];
#pragma unroll
    for (int i = 1; i < 8; ++i) tmax = fmaxf(tmax, mlds[i * 33 + q]);

    if (__any(tmax > m_run + 8.0f)) {
      const float mnew = fmaxf(m_run, tmax);
      const float f = __builtin_amdgcn_exp2f(m_run - mnew);
#pragma unroll
      for (int r = 0; r < 16; ++r) { accA[r] *= f; accB[r] *= f; }
      l_run *= f;
      m_run = mnew;
    }

#pragma unroll
    for (int r = 0; r < 16; ++r) st[r] = __builtin_amdgcn_exp2f(st[r] - m_run);
    float s0 = ((st[0] + st[1]) + (st[2] + st[3])) +
               ((st[4] + st[5]) + (st[6] + st[7]));
    float s1 = ((st[8] + st[9]) + (st[10] + st[11])) +
               ((st[12] + st[13]) + (st[14] + st[15]));
    float pssum = s0 + s1;
    float pa = pssum, pb = pssum;
    perm32swap_f(pa, pb);
    if (lane < 32) slds[w * 33 + q] = pa + pb;

#pragma unroll
    for (int rg = 0; rg < 4; ++rg) {
      const int pk = pack4_fp8(st[rg * 4], st[rg * 4 + 1], st[rg * 4 + 2], st[rg * 4 + 3]);
      *reinterpret_cast<int*>(&pbuf[pnext][q * 264 + w * 32 + rg * 8 + h * 4]) = pk;
    }
    __syncthreads();  // B2: P(t) + sums visible

    float tsum = slds[q];
#pragma unroll
    for (int i = 1; i < 8; ++i) tsum += slds[i * 33 + q];
    l_run += tsum;
  }

  // ---------------- epilogue: PV(15) ---------------------------------------
  {
    const unsigned char* vc = vtb + (size_t)(15 * 16) * 512 + lane * 8;
    __builtin_amdgcn_s_setprio(1);
#pragma unroll
    for (int kp = 0; kp < 8; ++kp) {
      const long vfA = *reinterpret_cast<const long*>(vc + (2 * kp) * 512);
      const long pfA = *reinterpret_cast<const long*>(&pbuf[1][q * 264 + (2 * kp) * 16 + h * 8]);
      accA = __builtin_amdgcn_mfma_f32_32x32x16_fp8_fp8(vfA, pfA, accA, 0, 0, 0);
      const long vfB = *reinterpret_cast<const long*>(vc + (2 * kp + 1) * 512);
      const long pfB = *reinterpret_cast<const long*>(&pbuf[1][q * 264 + (2 * kp + 1) * 16 + h * 8]);
      accB = __builtin_amdgcn_mfma_f32_32x32x16_fp8_fp8(vfB, pfB, accB, 0, 0, 0);
    }
    __builtin_amdgcn_s_setprio(0);
  }

  // ---- epilogue: out = gamma * O/l + x ----
  const float g = gamma[0];
  const float linv = 1.0f / l_run;
#pragma unroll
  for (int r = 0; r < 16; ++r) {
    const int c = w * 32 + (r & 3) + 8 * (r >> 2) + 4 * h;
    const size_t idx = ((size_t)b * CC + c) * NN + n0 + q;
    out[idx] = g * (accA[r] + accB[r]) * linv + x[idx];
  }
}

extern "C" void kernel_launch(void* const* d_in, const int* in_sizes, int n_in,
                              void* d_out, int out_size, void* d_ws, size_t ws_size,
                              hipStream_t stream) {
  const float* x = (const float*)d_in[0];
  const float* Wq = (const float*)d_in[1];
  const float* bq = (const float*)d_in[2];
  const float* Wk = (const float*)d_in[3];
  const float* bk = (const float*)d_in[4];
  const float* Wv = (const float*)d_in[5];
  const float* bv = (const float*)d_in[6];
  const float* gamma = (const float*)d_in[7];
  float* out = (float*)d_out;

  ushort* qT = (ushort*)d_ws;                          // B*128*1024 bf16
  ushort* kT = qT + (size_t)BB * 128 * 1024;           // B*128*1024 bf16
  unsigned char* vT8 = (unsigned char*)(kT + (size_t)BB * 128 * 1024);  // B*1MB fp8

  proj_mfma<<<dim3(BB, NN / 32), dim3(320), 0, stream>>>(
      Wq, bq, Wk, bk, Wv, bv, x, qT, kT, vT8);
  flash_coop<<<dim3(512), dim3(512), 0, stream>>>(
      qT, kT, vT8, x, gamma, out);
}

// Round 13
// 78.896 us; speedup vs baseline: 1.1159x; 1.1159x over previous
//
#include <hip/hip_runtime.h>
#include <hip/hip_bf16.h>
#include <cstddef>
#include <cstdint>

#define BB 4
#define CC 256
#define II 32
#define NN 4096

// 1/sqrt(32) * log2(e): fold softmax scale AND exp->exp2 conversion into q.
#define SCALE_Q 0.25505572751402893f

typedef __attribute__((ext_vector_type(8))) short bf16x8;
typedef __attribute__((ext_vector_type(16))) float f32x16;

static __device__ __forceinline__ int cvt_pk_bf16(float lo, float hi) {
  int d;
  asm("v_cvt_pk_bf16_f32 %0, %1, %2" : "=v"(d) : "v"(lo), "v"(hi));
  return d;
}
static __device__ __forceinline__ void perm32swap_f(float& a, float& b) {
  asm("v_permlane32_swap_b32 %0, %1" : "+v"(a), "+v"(b));
}
static __device__ __forceinline__ float max3f(float a, float b, float c) {
  float d;
  asm("v_max3_f32 %0, %1, %2, %3" : "=v"(d) : "v"(a), "v"(b), "v"(c));
  return d;
}
static __device__ __forceinline__ f32x16 zero16() {
  f32x16 z;
#pragma unroll
  for (int i = 0; i < 16; ++i) z[i] = 0.0f;
  return z;
}
// VGPR-form S-MFMA (keeps the softmax operand out of AGPRs).
static __device__ __forceinline__ void mfma_bf16_first(bf16x8 a, bf16x8 b, f32x16& c) {
  asm("s_nop 1\n\tv_mfma_f32_32x32x16_bf16 %0, %1, %2, %0"
      : "+v"(c) : "v"(a), "v"(b));
}
static __device__ __forceinline__ void mfma_bf16_last(bf16x8 a, bf16x8 b, f32x16& c) {
  asm("v_mfma_f32_32x32x16_bf16 %0, %1, %2, %0\n\ts_nop 7\n\ts_nop 7"
      : "+v"(c) : "v"(a), "v"(b));
}
static __device__ __forceinline__ bf16x8 pack8(float f0, float f1, float f2,
    float f3, float f4, float f5, float f6, float f7) {
  union { int w[4]; bf16x8 v8; } u;
  u.w[0] = cvt_pk_bf16(f0, f1);
  u.w[1] = cvt_pk_bf16(f2, f3);
  u.w[2] = cvt_pk_bf16(f4, f5);
  u.w[3] = cvt_pk_bf16(f6, f7);
  return u.v8;
}
static __device__ __forceinline__ ushort f2bfu(float f) {
  union { __hip_bfloat16 h; ushort u; } cv;
  cv.h = __float2bfloat16(f);
  return cv.u;
}
static __device__ __forceinline__ int pack4_fp8(float a, float b, float c, float d) {
  int r = __builtin_amdgcn_cvt_pk_fp8_f32(a, b, 0, false);
  r = __builtin_amdgcn_cvt_pk_fp8_f32(c, d, r, true);
  return r;
}
static __device__ __forceinline__ unsigned char f2fp8(float f) {
  return (unsigned char)(__builtin_amdgcn_cvt_pk_fp8_f32(f, f, 0, false) & 0xff);
}

// Layouts:
//  qT/kT (bf16): [b][mt=n/32][frag=i/16][p]; p = 256*((i>>3)&1) + 8*(n&31) + (i&7)
//  vT8  (fp8):   [b][ct=c/32][nt=n/16][p];  p = 256*((n>>3)&1) + 8*(c&31) + (n&7)
//                (ct-major: a wave's 16 PV loads are base + kt*512, contiguous)

// ---- fused qkv projection, MFMA 32x32x16, 1 wave/block ---------------------
// (round-7 z=5 structure — known good/fast; only the v-store index is ct-major)
__global__ __launch_bounds__(64, 3) void proj_mfma(
    const float* __restrict__ Wq, const float* __restrict__ bq,
    const float* __restrict__ Wk, const float* __restrict__ bk,
    const float* __restrict__ Wv, const float* __restrict__ bv,
    const float* __restrict__ x,
    ushort* __restrict__ qT, ushort* __restrict__ kT,
    unsigned char* __restrict__ vT8) {
  const int lane = threadIdx.x;
  const int l31 = lane & 31;
  const int h = lane >> 5;
  const int b = blockIdx.x;
  const int n0 = blockIdx.y * 32;
  const int og = blockIdx.z;

  const float* xb = x + (size_t)b * CC * NN + n0 + l31;
  const float* wr0 = (og == 0) ? (Wq + (size_t)l31 * CC)
                               : (Wv + (size_t)((og - 1) * 64 + l31) * CC);
  const float* wr1 = (og == 0) ? (Wk + (size_t)l31 * CC)
                               : (Wv + (size_t)((og - 1) * 64 + 32 + l31) * CC);

  f32x16 acc0 = zero16(), acc1 = zero16();
#pragma unroll 4
  for (int ks = 0; ks < 16; ++ks) {
    const int c = ks * 16 + h * 8;
    const float* xp = xb + (size_t)c * NN;
    bf16x8 xf = pack8(xp[0], xp[(size_t)1 * NN], xp[(size_t)2 * NN],
                      xp[(size_t)3 * NN], xp[(size_t)4 * NN], xp[(size_t)5 * NN],
                      xp[(size_t)6 * NN], xp[(size_t)7 * NN]);
    float4 wa = *(const float4*)(wr0 + c);
    float4 wb = *(const float4*)(wr0 + c + 4);
    bf16x8 wf0 = pack8(wa.x, wa.y, wa.z, wa.w, wb.x, wb.y, wb.z, wb.w);
    float4 wc = *(const float4*)(wr1 + c);
    float4 wd = *(const float4*)(wr1 + c + 4);
    bf16x8 wf1 = pack8(wc.x, wc.y, wc.z, wc.w, wd.x, wd.y, wd.z, wd.w);
    acc0 = __builtin_amdgcn_mfma_f32_32x32x16_bf16(wf0, xf, acc0, 0, 0, 0);
    acc1 = __builtin_amdgcn_mfma_f32_32x32x16_bf16(wf1, xf, acc1, 0, 0, 0);
  }

  if (og == 0) {
    ushort* qb = qT + (size_t)(b * 128 + (n0 >> 5)) * 1024;
    ushort* kb = kT + (size_t)(b * 128 + (n0 >> 5)) * 1024;
#pragma unroll
    for (int r = 0; r < 16; ++r) {
      const int i = (r & 3) + 8 * (r >> 2) + 4 * h;
      const size_t off = (size_t)(i >> 4) * 512 + ((i >> 3) & 1) * 256 + 8 * l31 + (i & 7);
      qb[off] = f2bfu((acc0[r] + bq[i]) * SCALE_Q);
      kb[off] = f2bfu(acc1[r] + bk[i]);
    }
  } else {
    const int n = n0 + l31;
    const size_t nsub = (size_t)(n >> 4) * 512 + ((size_t)((n >> 3) & 1)) * 256 + (n & 7);
    const size_t bbase = (size_t)b * (1 << 20);
#pragma unroll
    for (int r = 0; r < 16; ++r) {
      const int rp = (r & 3) + 8 * (r >> 2) + 4 * h;
      const int c0 = (og - 1) * 64 + rp;
      const int c1 = c0 + 32;
      vT8[bbase + (size_t)(c0 >> 5) * 131072 + nsub + (c0 & 31) * 8] = f2fp8(acc0[r] + bv[c0]);
      vT8[bbase + (size_t)(c1 >> 5) * 131072 + nsub + (c1 & 31) * 8] = f2fp8(acc1[r] + bv[c1]);
    }
  }
}

// ---- flash attention: 8-wave coop, pipelined + K-prefetch ------------------
// 1-D grid 512, block 512. Per iteration t: S(t) MFMA (K prefetched in iter
// t-1), issue K(t+1) loads, PV(t-1) MFMA, softmax(t) -> pbuf[t&1].
__global__ __launch_bounds__(512, 4) void flash_coop(
    const ushort* __restrict__ qT, const ushort* __restrict__ kT,
    const unsigned char* __restrict__ vT8, const float* __restrict__ x,
    const float* __restrict__ gamma, float* __restrict__ out) {
  __shared__ __align__(16) unsigned char pbuf[2][32 * 264];  // P fp8 [q][m_local]
  __shared__ float mlds[264];  // per-wave rowmax  [w*33 + q]
  __shared__ float slds[264];  // per-wave rowsum  [w*33 + q]

  const int tid = threadIdx.x;
  const int lane = tid & 63;
  const int w = tid >> 6;
  const int q = lane & 31;
  const int h = lane >> 5;

  const int wg = blockIdx.x;
  const int xcd = wg & 7;
  const int b = xcd >> 1;
  const int nt = ((xcd & 1) << 6) + (wg >> 3);
  const int n0 = nt * 32;

  const ushort* qb = qT + (size_t)(b * 128 + nt) * 1024 + lane * 8;
  const bf16x8 qf0 = *reinterpret_cast<const bf16x8*>(qb);
  const bf16x8 qf1 = *reinterpret_cast<const bf16x8*>(qb + 512);

  const ushort* ktb = kT + (size_t)b * 128 * 1024;
  const unsigned char* vtb = vT8 + (size_t)b * (1 << 20) + (size_t)w * 131072;

  f32x16 accA = zero16(), accB = zero16();
  float m_run = -1e30f, l_run = 0.0f;

  // ---------------- prologue: tile 0 S + softmax -> pbuf[0] ----------------
  {
    const ushort* kc = ktb + (size_t)(0 * 8 + w) * 1024 + lane * 8;
    const bf16x8 kf0 = *reinterpret_cast<const bf16x8*>(kc);
    const bf16x8 kf1 = *reinterpret_cast<const bf16x8*>(kc + 512);
    f32x16 st = zero16();
    mfma_bf16_first(kf0, qf0, st);
    mfma_bf16_last(kf1, qf1, st);

    float m0 = max3f(st[0], st[1], st[2]);
    float m1 = max3f(st[3], st[4], st[5]);
    float m2 = max3f(st[6], st[7], st[8]);
    float m3 = max3f(st[9], st[10], st[11]);
    m0 = max3f(st[12], st[13], m0);
    m1 = max3f(st[14], st[15], m1);
    float mx = max3f(m0, m1, fmaxf(m2, m3));
    float sw1 = mx, sw2 = mx;
    perm32swap_f(sw1, sw2);
    if (lane < 32) mlds[w * 33 + q] = fmaxf(sw1, sw2);
    __syncthreads();
    float tmax = mlds[q];
#pragma unroll
    for (int i = 1; i < 8; ++i) tmax = fmaxf(tmax, mlds[i * 33 + q]);
    m_run = tmax;

#pragma unroll
    for (int r = 0; r < 16; ++r) st[r] = __builtin_amdgcn_exp2f(st[r] - m_run);
    float s0 = ((st[0] + st[1]) + (st[2] + st[3])) +
               ((st[4] + st[5]) + (st[6] + st[7]));
    float s1 = ((st[8] + st[9]) + (st[10] + st[11])) +
               ((st[12] + st[13]) + (st[14] + st[15]));
    float pssum = s0 + s1;
    float pa = pssum, pb = pssum;
    perm32swap_f(pa, pb);
    if (lane < 32) slds[w * 33 + q] = pa + pb;
#pragma unroll
    for (int rg = 0; rg < 4; ++rg) {
      const int pk = pack4_fp8(st[rg * 4], st[rg * 4 + 1], st[rg * 4 + 2], st[rg * 4 + 3]);
      *reinterpret_cast<int*>(&pbuf[0][q * 264 + w * 32 + rg * 8 + h * 4]) = pk;
    }
    __syncthreads();
    float tsum = slds[q];
#pragma unroll
    for (int i = 1; i < 8; ++i) tsum += slds[i * 33 + q];
    l_run = tsum;
  }

  // K(1) prefetch (consumed at t=1)
  const ushort* kc1 = ktb + (size_t)(1 * 8 + w) * 1024 + lane * 8;
  bf16x8 kn0 = *reinterpret_cast<const bf16x8*>(kc1);
  bf16x8 kn1 = *reinterpret_cast<const bf16x8*>(kc1 + 512);

  // ---------------- main loop: t = 1..15 -----------------------------------
  for (int t = 1; t < 16; ++t) {
    const int pv = t - 1;           // PV consumes tile t-1
    const int pcur = pv & 1;
    const int pnext = t & 1;

    // issue K(t+1) prefetch FIRST (full-iteration issue-to-use distance)
    const int tn = (t < 15) ? t + 1 : 15;
    const ushort* kcn = ktb + (size_t)(tn * 8 + w) * 1024 + lane * 8;
    const bf16x8 kp0 = *reinterpret_cast<const bf16x8*>(kcn);
    const bf16x8 kp1 = *reinterpret_cast<const bf16x8*>(kcn + 512);

    // S(t) MFMA (K prefetched last iteration — no load-use stall)
    f32x16 st = zero16();
    __builtin_amdgcn_s_setprio(1);
    mfma_bf16_first(kn0, qf0, st);
    mfma_bf16_last(kn1, qf1, st);

    // PV(t-1): two independent chains, contiguous V (base + kt*512)
    const unsigned char* vc = vtb + (size_t)(pv * 16) * 512 + lane * 8;
#pragma unroll
    for (int kp = 0; kp < 8; ++kp) {
      const long vfA = *reinterpret_cast<const long*>(vc + (2 * kp) * 512);
      const long pfA = *reinterpret_cast<const long*>(&pbuf[pcur][q * 264 + (2 * kp) * 16 + h * 8]);
      accA = __builtin_amdgcn_mfma_f32_32x32x16_fp8_fp8(vfA, pfA, accA, 0, 0, 0);
      const long vfB = *reinterpret_cast<const long*>(vc + (2 * kp + 1) * 512);
      const long pfB = *reinterpret_cast<const long*>(&pbuf[pcur][q * 264 + (2 * kp + 1) * 16 + h * 8]);
      accB = __builtin_amdgcn_mfma_f32_32x32x16_fp8_fp8(vfB, pfB, accB, 0, 0, 0);
    }
    __builtin_amdgcn_s_setprio(0);

    // softmax(t)
    float m0 = max3f(st[0], st[1], st[2]);
    float m1 = max3f(st[3], st[4], st[5]);
    float m2 = max3f(st[6], st[7], st[8]);
    float m3 = max3f(st[9], st[10], st[11]);
    m0 = max3f(st[12], st[13], m0);
    m1 = max3f(st[14], st[15], m1);
    float mx = max3f(m0, m1, fmaxf(m2, m3));
    float sw1 = mx, sw2 = mx;
    perm32swap_f(sw1, sw2);
    if (lane < 32) mlds[w * 33 + q] = fmaxf(sw1, sw2);
    __syncthreads();  // B1: mlds(t) ready
    float tmax = mlds[q];
#pragma unroll
    for (int i = 1; i < 8; ++i) tmax = fmaxf(tmax, mlds[i * 33 + q]);

    if (__any(tmax > m_run + 8.0f)) {
      const float mnew = fmaxf(m_run, tmax);
      const float f = __builtin_amdgcn_exp2f(m_run - mnew);
#pragma unroll
      for (int r = 0; r < 16; ++r) { accA[r] *= f; accB[r] *= f; }
      l_run *= f;
      m_run = mnew;
    }

#pragma unroll
    for (int r = 0; r < 16; ++r) st[r] = __builtin_amdgcn_exp2f(st[r] - m_run);
    float s0 = ((st[0] + st[1]) + (st[2] + st[3])) +
               ((st[4] + st[5]) + (st[6] + st[7]));
    float s1 = ((st[8] + st[9]) + (st[10] + st[11])) +
               ((st[12] + st[13]) + (st[14] + st[15]));
    float pssum = s0 + s1;
    float pa = pssum, pb = pssum;
    perm32swap_f(pa, pb);
    if (lane < 32) slds[w * 33 + q] = pa + pb;

#pragma unroll
    for (int rg = 0; rg < 4; ++rg) {
      const int pk = pack4_fp8(st[rg * 4], st[rg * 4 + 1], st[rg * 4 + 2], st[rg * 4 + 3]);
      *reinterpret_cast<int*>(&pbuf[pnext][q * 264 + w * 32 + rg * 8 + h * 4]) = pk;
    }
    __syncthreads();  // B2: P(t) + sums visible

    float tsum = slds[q];
#pragma unroll
    for (int i = 1; i < 8; ++i) tsum += slds[i * 33 + q];
    l_run += tsum;

    kn0 = kp0;  // rotate K prefetch
    kn1 = kp1;
  }

  // ---------------- epilogue: PV(15) ---------------------------------------
  {
    const unsigned char* vc = vtb + (size_t)(15 * 16) * 512 + lane * 8;
    __builtin_amdgcn_s_setprio(1);
#pragma unroll
    for (int kp = 0; kp < 8; ++kp) {
      const long vfA = *reinterpret_cast<const long*>(vc + (2 * kp) * 512);
      const long pfA = *reinterpret_cast<const long*>(&pbuf[1][q * 264 + (2 * kp) * 16 + h * 8]);
      accA = __builtin_amdgcn_mfma_f32_32x32x16_fp8_fp8(vfA, pfA, accA, 0, 0, 0);
      const long vfB = *reinterpret_cast<const long*>(vc + (2 * kp + 1) * 512);
      const long pfB = *reinterpret_cast<const long*>(&pbuf[1][q * 264 + (2 * kp + 1) * 16 + h * 8]);
      accB = __builtin_amdgcn_mfma_f32_32x32x16_fp8_fp8(vfB, pfB, accB, 0, 0, 0);
    }
    __builtin_amdgcn_s_setprio(0);
  }

  // ---- epilogue: out = gamma * O/l + x ----
  const float g = gamma[0];
  const float linv = 1.0f / l_run;
#pragma unroll
  for (int r = 0; r < 16; ++r) {
    const int c = w * 32 + (r & 3) + 8 * (r >> 2) + 4 * h;
    const size_t idx = ((size_t)b * CC + c) * NN + n0 + q;
    out[idx] = g * (accA[r] + accB[r]) * linv + x[idx];
  }
}

extern "C" void kernel_launch(void* const* d_in, const int* in_sizes, int n_in,
                              void* d_out, int out_size, void* d_ws, size_t ws_size,
                              hipStream_t stream) {
  const float* x = (const float*)d_in[0];
  const float* Wq = (const float*)d_in[1];
  const float* bq = (const float*)d_in[2];
  const float* Wk = (const float*)d_in[3];
  const float* bk = (const float*)d_in[4];
  const float* Wv = (const float*)d_in[5];
  const float* bv = (const float*)d_in[6];
  const float* gamma = (const float*)d_in[7];
  float* out = (float*)d_out;

  ushort* qT = (ushort*)d_ws;                          // B*128*1024 bf16
  ushort* kT = qT + (size_t)BB * 128 * 1024;           // B*128*1024 bf16
  unsigned char* vT8 = (unsigned char*)(kT + (size_t)BB * 128 * 1024);  // B*1MB fp8

  proj_mfma<<<dim3(BB, NN / 32, 5), dim3(64), 0, stream>>>(
      Wq, bq, Wk, bk, Wv, bv, x, qT, kT, vT8);
  flash_coop<<<dim3(512), dim3(512), 0, stream>>>(
      qT, kT, vT8, x, gamma, out);
}

// Round 14
// 77.420 us; speedup vs baseline: 1.1372x; 1.0191x over previous
//
#include <hip/hip_runtime.h>
#include <hip/hip_bf16.h>
#include <cstddef>
#include <cstdint>

#define BB 4
#define CC 256
#define II 32
#define NN 4096

// 1/sqrt(32) * log2(e): fold softmax scale AND exp->exp2 conversion into q.
#define SCALE_Q 0.25505572751402893f

typedef __attribute__((ext_vector_type(8))) short bf16x8;
typedef __attribute__((ext_vector_type(16))) float f32x16;

static __device__ __forceinline__ int cvt_pk_bf16(float lo, float hi) {
  int d;
  asm("v_cvt_pk_bf16_f32 %0, %1, %2" : "=v"(d) : "v"(lo), "v"(hi));
  return d;
}
static __device__ __forceinline__ void perm32swap_f(float& a, float& b) {
  asm("v_permlane32_swap_b32 %0, %1" : "+v"(a), "+v"(b));
}
static __device__ __forceinline__ float max3f(float a, float b, float c) {
  float d;
  asm("v_max3_f32 %0, %1, %2, %3" : "=v"(d) : "v"(a), "v"(b), "v"(c));
  return d;
}
static __device__ __forceinline__ f32x16 zero16() {
  f32x16 z;
#pragma unroll
  for (int i = 0; i < 16; ++i) z[i] = 0.0f;
  return z;
}
// VGPR-form S-MFMA (keeps the softmax operand out of AGPRs).
static __device__ __forceinline__ void mfma_bf16_first(bf16x8 a, bf16x8 b, f32x16& c) {
  asm("s_nop 1\n\tv_mfma_f32_32x32x16_bf16 %0, %1, %2, %0"
      : "+v"(c) : "v"(a), "v"(b));
}
static __device__ __forceinline__ void mfma_bf16_last(bf16x8 a, bf16x8 b, f32x16& c) {
  asm("v_mfma_f32_32x32x16_bf16 %0, %1, %2, %0\n\ts_nop 7\n\ts_nop 7"
      : "+v"(c) : "v"(a), "v"(b));
}
static __device__ __forceinline__ bf16x8 pack8(float f0, float f1, float f2,
    float f3, float f4, float f5, float f6, float f7) {
  union { int w[4]; bf16x8 v8; } u;
  u.w[0] = cvt_pk_bf16(f0, f1);
  u.w[1] = cvt_pk_bf16(f2, f3);
  u.w[2] = cvt_pk_bf16(f4, f5);
  u.w[3] = cvt_pk_bf16(f6, f7);
  return u.v8;
}
static __device__ __forceinline__ ushort f2bfu(float f) {
  union { __hip_bfloat16 h; ushort u; } cv;
  cv.h = __float2bfloat16(f);
  return cv.u;
}
static __device__ __forceinline__ int pack4_fp8(float a, float b, float c, float d) {
  int r = __builtin_amdgcn_cvt_pk_fp8_f32(a, b, 0, false);
  r = __builtin_amdgcn_cvt_pk_fp8_f32(c, d, r, true);
  return r;
}
static __device__ __forceinline__ unsigned char f2fp8(float f) {
  return (unsigned char)(__builtin_amdgcn_cvt_pk_fp8_f32(f, f, 0, false) & 0xff);
}

// Layouts:
//  qT/kT (bf16): [b][mt=n/32][frag=i/16][p]; p = 256*((i>>3)&1) + 8*(n&31) + (i&7)
//  vT8  (fp8):   [b][ct=c/32][nt=n/16][p];  p = 256*((n>>3)&1) + 8*(c&31) + (n&7)
//                (ct-major: a wave's 16 PV loads are base + kt*512, contiguous)

// ---- fused qkv projection, MFMA 32x32x16, 1 wave/block ---------------------
// (round-7 z=5 structure — known good/fast; v-store index is ct-major)
__global__ __launch_bounds__(64, 3) void proj_mfma(
    const float* __restrict__ Wq, const float* __restrict__ bq,
    const float* __restrict__ Wk, const float* __restrict__ bk,
    const float* __restrict__ Wv, const float* __restrict__ bv,
    const float* __restrict__ x,
    ushort* __restrict__ qT, ushort* __restrict__ kT,
    unsigned char* __restrict__ vT8) {
  const int lane = threadIdx.x;
  const int l31 = lane & 31;
  const int h = lane >> 5;
  const int b = blockIdx.x;
  const int n0 = blockIdx.y * 32;
  const int og = blockIdx.z;

  const float* xb = x + (size_t)b * CC * NN + n0 + l31;
  const float* wr0 = (og == 0) ? (Wq + (size_t)l31 * CC)
                               : (Wv + (size_t)((og - 1) * 64 + l31) * CC);
  const float* wr1 = (og == 0) ? (Wk + (size_t)l31 * CC)
                               : (Wv + (size_t)((og - 1) * 64 + 32 + l31) * CC);

  f32x16 acc0 = zero16(), acc1 = zero16();
#pragma unroll 4
  for (int ks = 0; ks < 16; ++ks) {
    const int c = ks * 16 + h * 8;
    const float* xp = xb + (size_t)c * NN;
    bf16x8 xf = pack8(xp[0], xp[(size_t)1 * NN], xp[(size_t)2 * NN],
                      xp[(size_t)3 * NN], xp[(size_t)4 * NN], xp[(size_t)5 * NN],
                      xp[(size_t)6 * NN], xp[(size_t)7 * NN]);
    float4 wa = *(const float4*)(wr0 + c);
    float4 wb = *(const float4*)(wr0 + c + 4);
    bf16x8 wf0 = pack8(wa.x, wa.y, wa.z, wa.w, wb.x, wb.y, wb.z, wb.w);
    float4 wc = *(const float4*)(wr1 + c);
    float4 wd = *(const float4*)(wr1 + c + 4);
    bf16x8 wf1 = pack8(wc.x, wc.y, wc.z, wc.w, wd.x, wd.y, wd.z, wd.w);
    acc0 = __builtin_amdgcn_mfma_f32_32x32x16_bf16(wf0, xf, acc0, 0, 0, 0);
    acc1 = __builtin_amdgcn_mfma_f32_32x32x16_bf16(wf1, xf, acc1, 0, 0, 0);
  }

  if (og == 0) {
    ushort* qb = qT + (size_t)(b * 128 + (n0 >> 5)) * 1024;
    ushort* kb = kT + (size_t)(b * 128 + (n0 >> 5)) * 1024;
#pragma unroll
    for (int r = 0; r < 16; ++r) {
      const int i = (r & 3) + 8 * (r >> 2) + 4 * h;
      const size_t off = (size_t)(i >> 4) * 512 + ((i >> 3) & 1) * 256 + 8 * l31 + (i & 7);
      qb[off] = f2bfu((acc0[r] + bq[i]) * SCALE_Q);
      kb[off] = f2bfu(acc1[r] + bk[i]);
    }
  } else {
    const int n = n0 + l31;
    const size_t nsub = (size_t)(n >> 4) * 512 + ((size_t)((n >> 3) & 1)) * 256 + (n & 7);
    const size_t bbase = (size_t)b * (1 << 20);
#pragma unroll
    for (int r = 0; r < 16; ++r) {
      const int rp = (r & 3) + 8 * (r >> 2) + 4 * h;
      const int c0 = (og - 1) * 64 + rp;
      const int c1 = c0 + 32;
      vT8[bbase + (size_t)(c0 >> 5) * 131072 + nsub + (c0 & 31) * 8] = f2fp8(acc0[r] + bv[c0]);
      vT8[bbase + (size_t)(c1 >> 5) * 131072 + nsub + (c1 & 31) * 8] = f2fp8(acc1[r] + bv[c1]);
    }
  }
}

// ---- flash attention: 8-wave coop, V register double-buffer ----------------
// 1-D grid 512, block 512. Iter t: K(t) loads issue -> PV(t-1) (V in regs,
// pbuf reads software-pipelined) -> V(t) reg-prefetch -> S(t) -> softmax(t).
__global__ __launch_bounds__(512, 4) void flash_coop(
    const ushort* __restrict__ qT, const ushort* __restrict__ kT,
    const unsigned char* __restrict__ vT8, const float* __restrict__ x,
    const float* __restrict__ gamma, float* __restrict__ out) {
  __shared__ __align__(16) unsigned char pbuf[2][32 * 264];  // P fp8 [q][m_local]
  __shared__ float mlds[264];  // per-wave rowmax  [w*33 + q]
  __shared__ float slds[264];  // per-wave rowsum  [w*33 + q]

  const int tid = threadIdx.x;
  const int lane = tid & 63;
  const int w = tid >> 6;
  const int q = lane & 31;
  const int h = lane >> 5;

  const int wg = blockIdx.x;
  const int xcd = wg & 7;
  const int b = xcd >> 1;
  const int nt = ((xcd & 1) << 6) + (wg >> 3);
  const int n0 = nt * 32;

  const ushort* qb = qT + (size_t)(b * 128 + nt) * 1024 + lane * 8;
  const bf16x8 qf0 = *reinterpret_cast<const bf16x8*>(qb);
  const bf16x8 qf1 = *reinterpret_cast<const bf16x8*>(qb + 512);

  const ushort* ktb = kT + (size_t)b * 128 * 1024;
  const unsigned char* vtb = vT8 + (size_t)b * (1 << 20) + (size_t)w * 131072 + lane * 8;

  f32x16 accA = zero16(), accB = zero16();
  float m_run = -1e30f, l_run = 0.0f;
  long vregA[8], vregB[8];  // V double-buffer (static addresses, full-iter prefetch)

  // ---------------- prologue: tile 0 S + softmax -> pbuf[0] ----------------
  {
    const ushort* kc = ktb + (size_t)(0 * 8 + w) * 1024 + lane * 8;
    const bf16x8 kf0 = *reinterpret_cast<const bf16x8*>(kc);
    const bf16x8 kf1 = *reinterpret_cast<const bf16x8*>(kc + 512);
    f32x16 st = zero16();
    mfma_bf16_first(kf0, qf0, st);
    mfma_bf16_last(kf1, qf1, st);

    // V(0) prefetch (consumed by PV(0) in iter t=1)
#pragma unroll
    for (int kp = 0; kp < 8; ++kp) {
      vregA[kp] = *reinterpret_cast<const long*>(vtb + (2 * kp) * 512);
      vregB[kp] = *reinterpret_cast<const long*>(vtb + (2 * kp + 1) * 512);
    }

    float m0 = max3f(st[0], st[1], st[2]);
    float m1 = max3f(st[3], st[4], st[5]);
    float m2 = max3f(st[6], st[7], st[8]);
    float m3 = max3f(st[9], st[10], st[11]);
    m0 = max3f(st[12], st[13], m0);
    m1 = max3f(st[14], st[15], m1);
    float mx = max3f(m0, m1, fmaxf(m2, m3));
    float sw1 = mx, sw2 = mx;
    perm32swap_f(sw1, sw2);
    if (lane < 32) mlds[w * 33 + q] = fmaxf(sw1, sw2);
    __syncthreads();
    float tmax = mlds[q];
#pragma unroll
    for (int i = 1; i < 8; ++i) tmax = fmaxf(tmax, mlds[i * 33 + q]);
    m_run = tmax;

#pragma unroll
    for (int r = 0; r < 16; ++r) st[r] = __builtin_amdgcn_exp2f(st[r] - m_run);
    float s0 = ((st[0] + st[1]) + (st[2] + st[3])) +
               ((st[4] + st[5]) + (st[6] + st[7]));
    float s1 = ((st[8] + st[9]) + (st[10] + st[11])) +
               ((st[12] + st[13]) + (st[14] + st[15]));
    float pssum = s0 + s1;
    float pa = pssum, pb = pssum;
    perm32swap_f(pa, pb);
    if (lane < 32) slds[w * 33 + q] = pa + pb;
#pragma unroll
    for (int rg = 0; rg < 4; ++rg) {
      const int pk = pack4_fp8(st[rg * 4], st[rg * 4 + 1], st[rg * 4 + 2], st[rg * 4 + 3]);
      *reinterpret_cast<int*>(&pbuf[0][q * 264 + w * 32 + rg * 8 + h * 4]) = pk;
    }
    __syncthreads();
    float tsum = slds[q];
#pragma unroll
    for (int i = 1; i < 8; ++i) tsum += slds[i * 33 + q];
    l_run = tsum;
  }

  // ---------------- main loop: t = 1..15 -----------------------------------
  for (int t = 1; t < 16; ++t) {
    const int pv = t - 1;           // PV consumes tile t-1
    const int pcur = pv & 1;
    const int pnext = t & 1;

    // K(t) loads issue here; consumed by S(t) AFTER PV — latency hidden
    const ushort* kc = ktb + (size_t)(t * 8 + w) * 1024 + lane * 8;
    const bf16x8 kf0 = *reinterpret_cast<const bf16x8*>(kc);
    const bf16x8 kf1 = *reinterpret_cast<const bf16x8*>(kc + 512);

    // PV(t-1): V from registers, pbuf reads software-pipelined (depth 1)
    const unsigned char* pb = &pbuf[pcur][q * 264 + h * 8];
    __builtin_amdgcn_s_setprio(1);
    long pA = *reinterpret_cast<const long*>(pb);
    long pB = *reinterpret_cast<const long*>(pb + 16);
#pragma unroll
    for (int kp = 0; kp < 8; ++kp) {
      long pAn = 0, pBn = 0;
      if (kp < 7) {
        pAn = *reinterpret_cast<const long*>(pb + (2 * kp + 2) * 16);
        pBn = *reinterpret_cast<const long*>(pb + (2 * kp + 3) * 16);
      }
      accA = __builtin_amdgcn_mfma_f32_32x32x16_fp8_fp8(vregA[kp], pA, accA, 0, 0, 0);
      accB = __builtin_amdgcn_mfma_f32_32x32x16_fp8_fp8(vregB[kp], pB, accB, 0, 0, 0);
      pA = pAn; pB = pBn;
    }

    // V(t) prefetch (consumed by PV(t) next iteration / epilogue)
    const unsigned char* vcn = vtb + (size_t)(t * 16) * 512;
#pragma unroll
    for (int kp = 0; kp < 8; ++kp) {
      vregA[kp] = *reinterpret_cast<const long*>(vcn + (2 * kp) * 512);
      vregB[kp] = *reinterpret_cast<const long*>(vcn + (2 * kp + 1) * 512);
    }

    // S(t) MFMA (K arrived during PV)
    f32x16 st = zero16();
    mfma_bf16_first(kf0, qf0, st);
    mfma_bf16_last(kf1, qf1, st);
    __builtin_amdgcn_s_setprio(0);

    // softmax(t)
    float m0 = max3f(st[0], st[1], st[2]);
    float m1 = max3f(st[3], st[4], st[5]);
    float m2 = max3f(st[6], st[7], st[8]);
    float m3 = max3f(st[9], st[10], st[11]);
    m0 = max3f(st[12], st[13], m0);
    m1 = max3f(st[14], st[15], m1);
    float mx = max3f(m0, m1, fmaxf(m2, m3));
    float sw1 = mx, sw2 = mx;
    perm32swap_f(sw1, sw2);
    if (lane < 32) mlds[w * 33 + q] = fmaxf(sw1, sw2);
    __syncthreads();  // B1: mlds(t) ready
    float tmax = mlds[q];
#pragma unroll
    for (int i = 1; i < 8; ++i) tmax = fmaxf(tmax, mlds[i * 33 + q]);

    if (__any(tmax > m_run + 8.0f)) {
      const float mnew = fmaxf(m_run, tmax);
      const float f = __builtin_amdgcn_exp2f(m_run - mnew);
#pragma unroll
      for (int r = 0; r < 16; ++r) { accA[r] *= f; accB[r] *= f; }
      l_run *= f;
      m_run = mnew;
    }

#pragma unroll
    for (int r = 0; r < 16; ++r) st[r] = __builtin_amdgcn_exp2f(st[r] - m_run);
    float s0 = ((st[0] + st[1]) + (st[2] + st[3])) +
               ((st[4] + st[5]) + (st[6] + st[7]));
    float s1 = ((st[8] + st[9]) + (st[10] + st[11])) +
               ((st[12] + st[13]) + (st[14] + st[15]));
    float pssum = s0 + s1;
    float pa = pssum, pb2 = pssum;
    perm32swap_f(pa, pb2);
    if (lane < 32) slds[w * 33 + q] = pa + pb2;

#pragma unroll
    for (int rg = 0; rg < 4; ++rg) {
      const int pk = pack4_fp8(st[rg * 4], st[rg * 4 + 1], st[rg * 4 + 2], st[rg * 4 + 3]);
      *reinterpret_cast<int*>(&pbuf[pnext][q * 264 + w * 32 + rg * 8 + h * 4]) = pk;
    }
    __syncthreads();  // B2: P(t) + sums visible

    float tsum = slds[q];
#pragma unroll
    for (int i = 1; i < 8; ++i) tsum += slds[i * 33 + q];
    l_run += tsum;
  }

  // ---------------- epilogue: PV(15) (V already in registers) --------------
  {
    const unsigned char* pb = &pbuf[1][q * 264 + h * 8];
    __builtin_amdgcn_s_setprio(1);
#pragma unroll
    for (int kp = 0; kp < 8; ++kp) {
      const long pA = *reinterpret_cast<const long*>(pb + (2 * kp) * 16);
      const long pB = *reinterpret_cast<const long*>(pb + (2 * kp + 1) * 16);
      accA = __builtin_amdgcn_mfma_f32_32x32x16_fp8_fp8(vregA[kp], pA, accA, 0, 0, 0);
      accB = __builtin_amdgcn_mfma_f32_32x32x16_fp8_fp8(vregB[kp], pB, accB, 0, 0, 0);
    }
    __builtin_amdgcn_s_setprio(0);
  }

  // ---- epilogue: out = gamma * O/l + x ----
  const float g = gamma[0];
  const float linv = 1.0f / l_run;
#pragma unroll
  for (int r = 0; r < 16; ++r) {
    const int c = w * 32 + (r & 3) + 8 * (r >> 2) + 4 * h;
    const size_t idx = ((size_t)b * CC + c) * NN + n0 + q;
    out[idx] = g * (accA[r] + accB[r]) * linv + x[idx];
  }
}

extern "C" void kernel_launch(void* const* d_in, const int* in_sizes, int n_in,
                              void* d_out, int out_size, void* d_ws, size_t ws_size,
                              hipStream_t stream) {
  const float* x = (const float*)d_in[0];
  const float* Wq = (const float*)d_in[1];
  const float* bq = (const float*)d_in[2];
  const float* Wk = (const float*)d_in[3];
  const float* bk = (const float*)d_in[4];
  const float* Wv = (const float*)d_in[5];
  const float* bv = (const float*)d_in[6];
  const float* gamma = (const float*)d_in[7];
  float* out = (float*)d_out;

  ushort* qT = (ushort*)d_ws;                          // B*128*1024 bf16
  ushort* kT = qT + (size_t)BB * 128 * 1024;           // B*128*1024 bf16
  unsigned char* vT8 = (unsigned char*)(kT + (size_t)BB * 128 * 1024);  // B*1MB fp8

  proj_mfma<<<dim3(BB, NN / 32, 5), dim3(64), 0, stream>>>(
      Wq, bq, Wk, bk, Wv, bv, x, qT, kT, vT8);
  flash_coop<<<dim3(512), dim3(512), 0, stream>>>(
      qT, kT, vT8, x, gamma, out);
}